// Round 1
// baseline (1969.399 us; speedup 1.0000x reference)
//
#include <hip/hip_runtime.h>
#include <hip/hip_bf16.h>
#include <stdint.h>

// ============================================================================
// AdaptiveEdgeDropping: out = matrix with top-k (k = E*pct/100) of
// (log_sigmoid(dp*(1-v) - g*v) + gumbel(key=42)) zeroed.
// Must be BIT-EXACT vs JAX-CPU reference:
//   - threefry2x32, partitionable mode (bits = w0^w1, counts=(0,i), key=(0,42))
//   - uniform: ((bits>>9)|0x3f800000) as float - 1; f*(max-min)+min; max(min,.)
//   - Cephes/Eigen expf + logf (XLA CPU polynomial rewrite, UNFUSED mul/add)
//   - XLA elemental log1p: |x|<1e-4 ? x*(1-0.5x) : log(1+x)
//   - top_k stable ties (lower index first)
// ============================================================================

#define NBINS_SHIFT 12          // bin = ou >> 12  -> 2^20 bins
#define NBINS (1u << 20)
#define LIST_CAP 262144u
#define TIES_TILE 6144

// ---------------- threefry2x32, key=(0,42), counts=(0,i), out = x0^x1 -------
__device__ __forceinline__ unsigned tf_bits(unsigned i) {
  const unsigned ks0 = 0u;
  const unsigned ks1 = 42u;
  const unsigned ks2 = 0x1BD11BDAu ^ 0u ^ 42u;
  unsigned x0 = 0u + ks0;      // counts1 (hi of 64-bit iota) = 0
  unsigned x1 = i + ks1;       // counts2 = i
#define TF_R(rot) { x0 += x1; x1 = (x1 << (rot)) | (x1 >> (32 - (rot))); x1 ^= x0; }
  TF_R(13) TF_R(15) TF_R(26) TF_R(6)
  x0 += ks1; x1 += ks2 + 1u;
  TF_R(17) TF_R(29) TF_R(16) TF_R(24)
  x0 += ks2; x1 += ks0 + 2u;
  TF_R(13) TF_R(15) TF_R(26) TF_R(6)
  x0 += ks0; x1 += ks1 + 3u;
  TF_R(17) TF_R(29) TF_R(16) TF_R(24)
  x0 += ks1; x1 += ks2 + 4u;
  TF_R(13) TF_R(15) TF_R(26) TF_R(6)
  x0 += ks2; x1 += ks0 + 5u;
#undef TF_R
  return x0 ^ x1;
}

// ---------------- jax.random.uniform(key, minval=1e-7, maxval=1-1e-7) ------
__device__ __forceinline__ float uniform_from_bits(unsigned bits) {
  unsigned fb = (bits >> 9) | 0x3f800000u;
  float f = __uint_as_float(fb) - 1.0f;              // exact
  const float minv = 1e-7f;                          // 0x33D6BF95
  const float maxv = __uint_as_float(0x3F7FFFFEu);   // f32(1.0 - 1e-7)
  float r = __fsub_rn(maxv, minv);                   // XLA const-folds in f32
  float u = __fadd_rn(__fmul_rn(f, r), minv);        // separate roundings
  return fmaxf(minv, u);
}

// ---------------- XLA-CPU Cephes expf (GenerateVF32Exp, unfused) -----------
__device__ __forceinline__ float xla_expf(float input) {
  const float exp_hi = 88.3762626647950f;
  const float exp_lo = -88.3762626647949f;
  float x = fminf(fmaxf(input, exp_lo), exp_hi);
  float fx = floorf(__fadd_rn(__fmul_rn(x, 1.44269504088896341f), 0.5f));
  float tmp = __fmul_rn(0.693359375f, fx);
  float z = __fmul_rn(-2.12194440e-4f, fx);
  x = __fsub_rn(x, tmp);
  x = __fsub_rn(x, z);
  z = __fmul_rn(x, x);
  float y = __fadd_rn(__fmul_rn(x, 1.9875691500e-4f), 1.3981999507e-3f);
  y = __fadd_rn(__fmul_rn(y, x), 8.3334519073e-3f);
  y = __fadd_rn(__fmul_rn(y, x), 4.1665795894e-2f);
  y = __fadd_rn(__fmul_rn(y, x), 1.6666665459e-1f);
  y = __fadd_rn(__fmul_rn(y, x), 5.0000001201e-1f);
  y = __fadd_rn(__fmul_rn(y, z), x);
  y = __fadd_rn(1.0f, y);
  int n = (int)fx;                       // FPToSI (fx integral)
  float p2n = __int_as_float((n + 0x7f) << 23);
  return fmaxf(__fmul_rn(y, p2n), input);
}

// ---------------- XLA-CPU Cephes logf (GenerateVF32Log, Estrin, unfused) ---
__device__ __forceinline__ float xla_logf(float input) {
  // only called with positive, finite, >= ~1e-7 inputs here
  float t0 = fmaxf(input, __uint_as_float(0x00800000u));   // cut denormals
  unsigned ib = __float_as_uint(t0);
  int emm0 = (int)(ib >> 23) - 0x7f;
  float e = __fadd_rn(1.0f, (float)emm0);                  // exact small ints
  float m = __uint_as_float((ib & 0x807fffffu) | 0x3f000000u); // mant | 0.5
  bool mask = m < 0.707106781186547524f;
  float t1 = mask ? m : 0.0f;
  m = __fsub_rn(m, 1.0f);
  e = __fsub_rn(e, mask ? 1.0f : 0.0f);
  m = __fadd_rn(m, t1);
  float x2 = __fmul_rn(m, m);
  float x3 = __fmul_rn(x2, m);
  // degree-8 poly in three parts (XLA comment: "improve ILP")
  float y  = __fadd_rn(__fmul_rn(m, 7.0376836292e-2f), -1.1514610310e-1f);
  float y1 = __fadd_rn(__fmul_rn(m, -1.2420140846e-1f), 1.4249322787e-1f);
  float y2 = __fadd_rn(__fmul_rn(m, 2.0000714765e-1f), -2.4999993993e-1f);
  y  = __fadd_rn(__fmul_rn(y, m), 1.1676998740e-1f);
  y1 = __fadd_rn(__fmul_rn(y1, m), -1.6668057665e-1f);
  y2 = __fadd_rn(__fmul_rn(y2, m), 3.3333331174e-1f);
  y = __fadd_rn(__fmul_rn(y, x3), y1);
  y = __fadd_rn(__fmul_rn(y, x3), y2);
  y = __fmul_rn(y, x3);
  y = __fadd_rn(y, __fmul_rn(-2.12194440e-4f, e));   // y += e*q1
  y = __fsub_rn(y, __fmul_rn(0.5f, x2));             // y -= 0.5*x2
  m = __fadd_rn(m, y);
  m = __fadd_rn(m, __fmul_rn(0.693359375f, e));      // x += e*q2
  return m;
}

// ---------------- XLA elemental log1p --------------------------------------
__device__ __forceinline__ float xla_log1pf(float x) {
  float for_large = xla_logf(__fadd_rn(x, 1.0f));
  float for_small = __fmul_rn(__fadd_rn(__fmul_rn(-0.5f, x), 1.0f), x);
  return (fabsf(x) < 1e-4f) ? for_small : for_large;
}

// ---------------- per-element orderable key --------------------------------
// key = log_sigmoid(dp*(1-v) - g*v) + (-log(-log(u)));  v==0 -> -inf (ou=0)
__device__ __forceinline__ unsigned compute_ou(unsigned i, float v, float dp, float g) {
  if (v == 0.0f) return 0u;
  unsigned bits = tf_bits(i);
  float u = uniform_from_bits(bits);
  float lg = xla_logf(u);                 // log(u) < 0
  float gum = -xla_logf(-lg);             // -log(-log u)
  float t = __fsub_rn(1.0f, v);
  float lx = __fsub_rn(__fmul_rn(dp, t), __fmul_rn(g, v));
  float ex = xla_expf(-fabsf(lx));
  float l1p = xla_log1pf(ex);
  float lp = -(__fadd_rn(fmaxf(-lx, 0.0f), l1p));   // log_sigmoid
  float key = __fadd_rn(lp, gum);
  unsigned b = __float_as_uint(key);
  return (b & 0x80000000u) ? ~b : (b | 0x80000000u);  // monotone order map
}

// ---------------- kernels ---------------------------------------------------
__global__ __launch_bounds__(256) void hist_kernel(
    const float* __restrict__ v, const float* __restrict__ dpp,
    const float* __restrict__ gp, unsigned* __restrict__ keys,
    unsigned* __restrict__ hist, int E) {
  float dp = dpp[0], g = gp[0];
  int stride = gridDim.x * blockDim.x;
  for (int i = blockIdx.x * blockDim.x + threadIdx.x; i < E; i += stride) {
    unsigned ou = compute_ou((unsigned)i, v[i], dp, g);
    if (keys) keys[i] = ou;
    atomicAdd(&hist[ou >> NBINS_SHIFT], 1u);
  }
}

__global__ __launch_bounds__(256) void reduce_kernel(
    const unsigned* __restrict__ hist, unsigned* __restrict__ chunksum) {
  __shared__ unsigned s[256];
  unsigned sum = 0;
  int base = blockIdx.x * 1024;
  for (int t = threadIdx.x; t < 1024; t += 256) sum += hist[base + t];
  s[threadIdx.x] = sum;
  __syncthreads();
  for (int off = 128; off > 0; off >>= 1) {
    if (threadIdx.x < off) s[threadIdx.x] += s[threadIdx.x + off];
    __syncthreads();
  }
  if (threadIdx.x == 0) chunksum[blockIdx.x] = s[0];
}

__global__ __launch_bounds__(1024) void findbin_kernel(
    const unsigned* __restrict__ chunksum, const unsigned* __restrict__ hist,
    unsigned* __restrict__ state, const int* __restrict__ pct_p, long long Etot) {
  __shared__ unsigned s[1024];
  __shared__ int chosenC, chosenB;
  int tid = threadIdx.x;
  long long k = (Etot * (long long)pct_p[0]) / 100;

  // suffix sums over 1024 chunk sums
  s[tid] = chunksum[tid];
  __syncthreads();
  for (int off = 1; off < 1024; off <<= 1) {
    unsigned add = (tid + off < 1024) ? s[tid + off] : 0u;
    __syncthreads();
    s[tid] += add;
    __syncthreads();
  }
  long long aboveT = (tid < 1023) ? (long long)s[tid + 1] : 0;
  if (aboveT < k && k <= (long long)s[tid]) chosenC = tid;
  __syncthreads();
  int C = chosenC;
  __syncthreads();
  long long aboveC = (C < 1023) ? (long long)s[C + 1] : 0;

  // suffix sums over the 1024 bins of chunk C
  s[tid] = hist[C * 1024 + tid];
  __syncthreads();
  for (int off = 1; off < 1024; off <<= 1) {
    unsigned add = (tid + off < 1024) ? s[tid + off] : 0u;
    __syncthreads();
    s[tid] += add;
    __syncthreads();
  }
  long long abv = aboveC + ((tid < 1023) ? (long long)s[tid + 1] : 0);
  if (abv < k && k <= aboveC + (long long)s[tid]) chosenB = tid;
  __syncthreads();
  if (tid == 0) {
    int Bl = chosenB;
    long long aboveB = aboveC + ((Bl < 1023) ? (long long)s[Bl + 1] : 0);
    unsigned B = (unsigned)(C * 1024 + Bl);
    state[0] = B;
    state[1] = (unsigned)(k - aboveB);                       // r in [1, hist[B]]
    state[2] = (B == NBINS - 1u) ? 0xFFFFFFFFu : ((B + 1u) << NBINS_SHIFT);
  }
}

__global__ __launch_bounds__(256) void output_kernel(
    const float* __restrict__ v, const float* __restrict__ dpp,
    const float* __restrict__ gp, const unsigned* __restrict__ keys,
    float* __restrict__ out, unsigned* __restrict__ state,
    uint2* __restrict__ list, int E) {
  unsigned B = state[0], bound = state[2];
  float dp = dpp[0], g = gp[0];
  int stride = gridDim.x * blockDim.x;
  for (int i = blockIdx.x * blockDim.x + threadIdx.x; i < E; i += stride) {
    float val = v[i];
    unsigned ou = keys ? keys[i] : compute_ou((unsigned)i, val, dp, g);
    float o = val;
    if (ou >= bound) {
      o = 0.0f;
    } else if ((ou >> NBINS_SHIFT) == B) {
      unsigned pos = atomicAdd(&state[3], 1u);
      if (pos < LIST_CAP) list[pos] = make_uint2(ou, (unsigned)i);
    }
    out[i] = o;
  }
}

__global__ __launch_bounds__(1024) void ties_kernel(
    const uint2* __restrict__ list, const unsigned* __restrict__ state,
    float* __restrict__ out) {
  __shared__ uint2 tile[TIES_TILE];
  unsigned M = min(state[3], LIST_CAP);
  unsigned r = state[1];
  int tid = threadIdx.x;
  for (unsigned e0 = 0; e0 < M; e0 += blockDim.x) {
    unsigned e = e0 + tid;
    bool valid = e < M;
    unsigned my_ou = 0, my_idx = 0;
    if (valid) { uint2 me = list[e]; my_ou = me.x; my_idx = me.y; }
    unsigned rank = 0;
    for (unsigned t0 = 0; t0 < M; t0 += TIES_TILE) {
      unsigned tn = min((unsigned)TIES_TILE, M - t0);
      __syncthreads();
      for (unsigned j = tid; j < tn; j += blockDim.x) tile[j] = list[t0 + j];
      __syncthreads();
      if (valid) {
        for (unsigned j = 0; j < tn; ++j) {
          uint2 o = tile[j];
          rank += (o.x > my_ou || (o.x == my_ou && o.y < my_idx)) ? 1u : 0u;
        }
      }
    }
    if (valid && rank < r) out[my_idx] = 0.0f;  // drop: rank by (key desc, idx asc)
  }
}

// ---------------- launch ----------------------------------------------------
extern "C" void kernel_launch(void* const* d_in, const int* in_sizes, int n_in,
                              void* d_out, int out_size, void* d_ws, size_t ws_size,
                              hipStream_t stream) {
  const float* v  = (const float*)d_in[0];
  const float* dp = (const float*)d_in[1];
  const float* g  = (const float*)d_in[2];
  const int* pct  = (const int*)d_in[3];
  float* out = (float*)d_out;
  int E = in_sizes[0];

  uint8_t* ws = (uint8_t*)d_ws;
  const size_t HIST_OFF = 0;
  const size_t CHUNK_OFF = (size_t)4 << 20;              // 4 MiB
  const size_t STATE_OFF = CHUNK_OFF + 4096;             // +4 KiB
  const size_t LIST_OFF = CHUNK_OFF + 8192;              // +8 KiB
  const size_t KEYS_OFF = (size_t)8 << 20;               // 8 MiB
  const size_t BASE_NEED = LIST_OFF + (size_t)LIST_CAP * 8;

  if (ws_size < BASE_NEED) {
    // Can't run selection without workspace; emit passthrough (will fail
    // validation loudly rather than corrupt memory).
    hipMemcpyAsync(out, v, (size_t)E * 4, hipMemcpyDeviceToDevice, stream);
    return;
  }

  unsigned* hist = (unsigned*)(ws + HIST_OFF);
  unsigned* chunksum = (unsigned*)(ws + CHUNK_OFF);
  unsigned* state = (unsigned*)(ws + STATE_OFF);
  uint2* list = (uint2*)(ws + LIST_OFF);
  bool use_keys = ws_size >= KEYS_OFF + (size_t)E * 4;
  unsigned* keys = use_keys ? (unsigned*)(ws + KEYS_OFF) : nullptr;

  // zero hist + chunksum + state (list is count-guarded)
  hipMemsetAsync(ws, 0, CHUNK_OFF + 8192, stream);

  hist_kernel<<<4096, 256, 0, stream>>>(v, dp, g, keys, hist, E);
  reduce_kernel<<<1024, 256, 0, stream>>>(hist, chunksum);
  findbin_kernel<<<1, 1024, 0, stream>>>(chunksum, hist, state, pct, (long long)E);
  output_kernel<<<4096, 256, 0, stream>>>(v, dp, g, keys, out, state, list, E);
  ties_kernel<<<1, 1024, 0, stream>>>(list, state, out);
}

// Round 2
// 207.336 us; speedup vs baseline: 9.4986x; 9.4986x over previous
//
#include <hip/hip_runtime.h>
#include <hip/hip_bf16.h>
#include <stdint.h>

// ============================================================================
// AdaptiveEdgeDropping: out = matrix with top-k (k = E*pct/100) of
// (log_sigmoid(dp*(1-v) - g*v) + gumbel(key=42)) zeroed.
// BIT-EXACT numerics vs JAX-CPU (verified round 1, absmax 0.0):
//   threefry2x32 partitionable, XLA-CPU Cephes expf/logf (unfused), XLA log1p,
//   stable top-k ties (lower index first).
// Selection: 2-level radix-select (12+12 bits of monotone-mapped key) with
// LDS-private histograms -> no per-element global atomics.
// ============================================================================

#define LIST_CAP 262144u
#define TIES_TILE 4096

// ---------------- threefry2x32, key=(0,42), counts=(0,i), out = x0^x1 -------
__device__ __forceinline__ unsigned tf_bits(unsigned i) {
  const unsigned ks0 = 0u;
  const unsigned ks1 = 42u;
  const unsigned ks2 = 0x1BD11BDAu ^ 0u ^ 42u;
  unsigned x0 = 0u + ks0;
  unsigned x1 = i + ks1;
#define TF_R(rot) { x0 += x1; x1 = (x1 << (rot)) | (x1 >> (32 - (rot))); x1 ^= x0; }
  TF_R(13) TF_R(15) TF_R(26) TF_R(6)
  x0 += ks1; x1 += ks2 + 1u;
  TF_R(17) TF_R(29) TF_R(16) TF_R(24)
  x0 += ks2; x1 += ks0 + 2u;
  TF_R(13) TF_R(15) TF_R(26) TF_R(6)
  x0 += ks0; x1 += ks1 + 3u;
  TF_R(17) TF_R(29) TF_R(16) TF_R(24)
  x0 += ks1; x1 += ks2 + 4u;
  TF_R(13) TF_R(15) TF_R(26) TF_R(6)
  x0 += ks2; x1 += ks0 + 5u;
#undef TF_R
  return x0 ^ x1;
}

// ---------------- jax.random.uniform(minval=1e-7, maxval=1-1e-7) -----------
__device__ __forceinline__ float uniform_from_bits(unsigned bits) {
  unsigned fb = (bits >> 9) | 0x3f800000u;
  float f = __uint_as_float(fb) - 1.0f;
  const float minv = 1e-7f;
  const float maxv = __uint_as_float(0x3F7FFFFEu);   // f32(1.0 - 1e-7)
  float r = __fsub_rn(maxv, minv);
  float u = __fadd_rn(__fmul_rn(f, r), minv);
  return fmaxf(minv, u);
}

// ---------------- XLA-CPU Cephes expf (unfused) ----------------------------
__device__ __forceinline__ float xla_expf(float input) {
  const float exp_hi = 88.3762626647950f;
  const float exp_lo = -88.3762626647949f;
  float x = fminf(fmaxf(input, exp_lo), exp_hi);
  float fx = floorf(__fadd_rn(__fmul_rn(x, 1.44269504088896341f), 0.5f));
  float tmp = __fmul_rn(0.693359375f, fx);
  float z = __fmul_rn(-2.12194440e-4f, fx);
  x = __fsub_rn(x, tmp);
  x = __fsub_rn(x, z);
  z = __fmul_rn(x, x);
  float y = __fadd_rn(__fmul_rn(x, 1.9875691500e-4f), 1.3981999507e-3f);
  y = __fadd_rn(__fmul_rn(y, x), 8.3334519073e-3f);
  y = __fadd_rn(__fmul_rn(y, x), 4.1665795894e-2f);
  y = __fadd_rn(__fmul_rn(y, x), 1.6666665459e-1f);
  y = __fadd_rn(__fmul_rn(y, x), 5.0000001201e-1f);
  y = __fadd_rn(__fmul_rn(y, z), x);
  y = __fadd_rn(1.0f, y);
  int n = (int)fx;
  float p2n = __int_as_float((n + 0x7f) << 23);
  return fmaxf(__fmul_rn(y, p2n), input);
}

// ---------------- XLA-CPU Cephes logf (Estrin, unfused) --------------------
__device__ __forceinline__ float xla_logf(float input) {
  float t0 = fmaxf(input, __uint_as_float(0x00800000u));
  unsigned ib = __float_as_uint(t0);
  int emm0 = (int)(ib >> 23) - 0x7f;
  float e = __fadd_rn(1.0f, (float)emm0);
  float m = __uint_as_float((ib & 0x807fffffu) | 0x3f000000u);
  bool mask = m < 0.707106781186547524f;
  float t1 = mask ? m : 0.0f;
  m = __fsub_rn(m, 1.0f);
  e = __fsub_rn(e, mask ? 1.0f : 0.0f);
  m = __fadd_rn(m, t1);
  float x2 = __fmul_rn(m, m);
  float x3 = __fmul_rn(x2, m);
  float y  = __fadd_rn(__fmul_rn(m, 7.0376836292e-2f), -1.1514610310e-1f);
  float y1 = __fadd_rn(__fmul_rn(m, -1.2420140846e-1f), 1.4249322787e-1f);
  float y2 = __fadd_rn(__fmul_rn(m, 2.0000714765e-1f), -2.4999993993e-1f);
  y  = __fadd_rn(__fmul_rn(y, m), 1.1676998740e-1f);
  y1 = __fadd_rn(__fmul_rn(y1, m), -1.6668057665e-1f);
  y2 = __fadd_rn(__fmul_rn(y2, m), 3.3333331174e-1f);
  y = __fadd_rn(__fmul_rn(y, x3), y1);
  y = __fadd_rn(__fmul_rn(y, x3), y2);
  y = __fmul_rn(y, x3);
  y = __fadd_rn(y, __fmul_rn(-2.12194440e-4f, e));
  y = __fsub_rn(y, __fmul_rn(0.5f, x2));
  m = __fadd_rn(m, y);
  m = __fadd_rn(m, __fmul_rn(0.693359375f, e));
  return m;
}

// ---------------- XLA elemental log1p --------------------------------------
__device__ __forceinline__ float xla_log1pf(float x) {
  float for_large = xla_logf(__fadd_rn(x, 1.0f));
  float for_small = __fmul_rn(__fadd_rn(__fmul_rn(-0.5f, x), 1.0f), x);
  return (fabsf(x) < 1e-4f) ? for_small : for_large;
}

// ---------------- per-element orderable key (monotone uint map) ------------
__device__ __forceinline__ unsigned compute_ou(unsigned i, float v, float dp, float g) {
  if (v == 0.0f) return 0u;
  unsigned bits = tf_bits(i);
  float u = uniform_from_bits(bits);
  float lg = xla_logf(u);
  float gum = -xla_logf(-lg);
  float t = __fsub_rn(1.0f, v);
  float lx = __fsub_rn(__fmul_rn(dp, t), __fmul_rn(g, v));
  float ex = xla_expf(-fabsf(lx));
  float l1p = xla_log1pf(ex);
  float lp = -(__fadd_rn(fmaxf(-lx, 0.0f), l1p));
  float key = __fadd_rn(lp, gum);
  unsigned b = __float_as_uint(key);
  return (b & 0x80000000u) ? ~b : (b | 0x80000000u);
}

// ============================================================================
// P1: compute keys (store), LDS histogram of top-12 bits, per-block flush.
// ============================================================================
__global__ __launch_bounds__(256) void key_hist1_kernel(
    const float* __restrict__ v, const float* __restrict__ dpp,
    const float* __restrict__ gp, unsigned* __restrict__ keys,
    unsigned* __restrict__ blockhist, int E) {
  __shared__ unsigned h[4096];
  for (int j = threadIdx.x; j < 4096; j += 256) h[j] = 0;
  __syncthreads();
  float dp = dpp[0], g = gp[0];
  int nvec = E >> 2;
  int stride = gridDim.x * 256;
  for (int iv = blockIdx.x * 256 + threadIdx.x; iv < nvec; iv += stride) {
    float4 vv = reinterpret_cast<const float4*>(v)[iv];
    unsigned base = (unsigned)iv << 2;
    unsigned o0 = compute_ou(base + 0u, vv.x, dp, g);
    unsigned o1 = compute_ou(base + 1u, vv.y, dp, g);
    unsigned o2 = compute_ou(base + 2u, vv.z, dp, g);
    unsigned o3 = compute_ou(base + 3u, vv.w, dp, g);
    if (keys) reinterpret_cast<uint4*>(keys)[iv] = make_uint4(o0, o1, o2, o3);
    atomicAdd(&h[o0 >> 20], 1u);
    atomicAdd(&h[o1 >> 20], 1u);
    atomicAdd(&h[o2 >> 20], 1u);
    atomicAdd(&h[o3 >> 20], 1u);
  }
  if (blockIdx.x == 0) {                       // tail (E % 4)
    for (int i = (nvec << 2) + threadIdx.x; i < E; i += 256) {
      unsigned ou = compute_ou((unsigned)i, v[i], dp, g);
      if (keys) keys[i] = ou;
      atomicAdd(&h[ou >> 20], 1u);
    }
  }
  __syncthreads();
  unsigned* row = blockhist + (size_t)blockIdx.x * 4096;
  for (int j = threadIdx.x; j < 4096; j += 256) row[j] = h[j];
}

// ============================================================================
// P2: histogram next-12 bits of coarse-bin-B1 members.
// ============================================================================
__global__ __launch_bounds__(256) void refine_hist_kernel(
    const float* __restrict__ v, const float* __restrict__ dpp,
    const float* __restrict__ gp, const unsigned* __restrict__ keys,
    const unsigned* __restrict__ state, unsigned* __restrict__ blockhist, int E) {
  __shared__ unsigned h[4096];
  for (int j = threadIdx.x; j < 4096; j += 256) h[j] = 0;
  __syncthreads();
  unsigned B1 = state[0];
  float dp = dpp[0], g = gp[0];
  int nvec = E >> 2;
  int stride = gridDim.x * 256;
  for (int iv = blockIdx.x * 256 + threadIdx.x; iv < nvec; iv += stride) {
    unsigned o0, o1, o2, o3;
    if (keys) {
      uint4 kk = reinterpret_cast<const uint4*>(keys)[iv];
      o0 = kk.x; o1 = kk.y; o2 = kk.z; o3 = kk.w;
    } else {
      float4 vv = reinterpret_cast<const float4*>(v)[iv];
      unsigned base = (unsigned)iv << 2;
      o0 = compute_ou(base + 0u, vv.x, dp, g);
      o1 = compute_ou(base + 1u, vv.y, dp, g);
      o2 = compute_ou(base + 2u, vv.z, dp, g);
      o3 = compute_ou(base + 3u, vv.w, dp, g);
    }
    if ((o0 >> 20) == B1) atomicAdd(&h[(o0 >> 8) & 0xFFFu], 1u);
    if ((o1 >> 20) == B1) atomicAdd(&h[(o1 >> 8) & 0xFFFu], 1u);
    if ((o2 >> 20) == B1) atomicAdd(&h[(o2 >> 8) & 0xFFFu], 1u);
    if ((o3 >> 20) == B1) atomicAdd(&h[(o3 >> 8) & 0xFFFu], 1u);
  }
  if (blockIdx.x == 0) {
    for (int i = (nvec << 2) + threadIdx.x; i < E; i += 256) {
      unsigned ou = keys ? keys[i] : compute_ou((unsigned)i, v[i], dp, g);
      if ((ou >> 20) == B1) atomicAdd(&h[(ou >> 8) & 0xFFFu], 1u);
    }
  }
  __syncthreads();
  unsigned* row = blockhist + (size_t)blockIdx.x * 4096;
  for (int j = threadIdx.x; j < 4096; j += 256) row[j] = h[j];
}

// ============================================================================
// R: hist[j] += sum_b blockhist[b][j]   (hist pre-zeroed; sliced atomics)
// ============================================================================
#define RED_SLICES 8
__global__ __launch_bounds__(256) void reduce_hist_kernel(
    const unsigned* __restrict__ blockhist, unsigned* __restrict__ hist, int NB) {
  int gid = blockIdx.x * 256 + threadIdx.x;   // 128 blocks -> 32768 threads
  int j = gid & 4095;
  int slice = gid >> 12;                      // 0..RED_SLICES-1
  unsigned s = 0;
  for (int b = slice; b < NB; b += RED_SLICES)
    s += blockhist[(size_t)b * 4096 + j];
  atomicAdd(&hist[j], s);
}

// ============================================================================
// F: single-block suffix-scan select over 4096 bins.
// stage 0: k = E*pct/100 -> state[0]=B1, state[1]=r1; zero hist for stage 2.
// stage 1: k = r1        -> state[2]=B2, state[3]=r2, state[5]=thresh24,
//                           state[4]=0 (list counter).
// ============================================================================
__global__ __launch_bounds__(1024) void findbin_kernel(
    unsigned* __restrict__ hist, unsigned* __restrict__ state,
    const int* __restrict__ pct_p, long long Etot, int stage) {
  __shared__ unsigned s[1024];
  int t = threadIdx.x;
  unsigned h0 = hist[4 * t + 0], h1 = hist[4 * t + 1];
  unsigned h2 = hist[4 * t + 2], h3 = hist[4 * t + 3];
  unsigned tot = h0 + h1 + h2 + h3;
  s[t] = tot;
  __syncthreads();
  for (int off = 1; off < 1024; off <<= 1) {
    unsigned add = (t + off < 1024) ? s[t + off] : 0u;
    __syncthreads();
    s[t] += add;
    __syncthreads();
  }
  long long k = (stage == 0) ? (Etot * (long long)pct_p[0]) / 100
                             : (long long)state[1];
  long long above_next = (t < 1023) ? (long long)s[t + 1] : 0;
  if (above_next < k && k <= above_next + (long long)tot) {
    unsigned hh[4] = {h0, h1, h2, h3};
    long long above = above_next;
    int b = 3;
    for (; b >= 0; --b) {
      if (above < k && k <= above + (long long)hh[b]) break;
      above += (long long)hh[b];
    }
    unsigned B = (unsigned)(4 * t + b);
    unsigned r = (unsigned)(k - above);
    if (stage == 0) {
      state[0] = B; state[1] = r;
    } else {
      state[2] = B; state[3] = r;
      state[5] = (state[0] << 12) | B;   // 24-bit threshold prefix
      state[4] = 0u;                     // list counter
    }
  }
  if (stage == 0) {                      // zero hist for the refine pass
    hist[4 * t + 0] = 0u; hist[4 * t + 1] = 0u;
    hist[4 * t + 2] = 0u; hist[4 * t + 3] = 0u;
  }
}

// ============================================================================
// P3: write output; collect exact-threshold-prefix ties.
// ============================================================================
__global__ __launch_bounds__(256) void output_kernel(
    const float* __restrict__ v, const float* __restrict__ dpp,
    const float* __restrict__ gp, const unsigned* __restrict__ keys,
    float* __restrict__ out, unsigned* __restrict__ state,
    uint2* __restrict__ list, int E) {
  unsigned thresh = state[5];
  float dp = dpp[0], g = gp[0];
  int nvec = E >> 2;
  int stride = gridDim.x * 256;
  for (int iv = blockIdx.x * 256 + threadIdx.x; iv < nvec; iv += stride) {
    float4 vv = reinterpret_cast<const float4*>(v)[iv];
    unsigned base = (unsigned)iv << 2;
    unsigned o0, o1, o2, o3;
    if (keys) {
      uint4 kk = reinterpret_cast<const uint4*>(keys)[iv];
      o0 = kk.x; o1 = kk.y; o2 = kk.z; o3 = kk.w;
    } else {
      o0 = compute_ou(base + 0u, vv.x, dp, g);
      o1 = compute_ou(base + 1u, vv.y, dp, g);
      o2 = compute_ou(base + 2u, vv.z, dp, g);
      o3 = compute_ou(base + 3u, vv.w, dp, g);
    }
    float4 oo;
    unsigned p;
    p = o0 >> 8; oo.x = (p > thresh) ? 0.0f : vv.x;
    if (p == thresh) { unsigned q = atomicAdd(&state[4], 1u); if (q < LIST_CAP) list[q] = make_uint2(o0, base + 0u); }
    p = o1 >> 8; oo.y = (p > thresh) ? 0.0f : vv.y;
    if (p == thresh) { unsigned q = atomicAdd(&state[4], 1u); if (q < LIST_CAP) list[q] = make_uint2(o1, base + 1u); }
    p = o2 >> 8; oo.z = (p > thresh) ? 0.0f : vv.z;
    if (p == thresh) { unsigned q = atomicAdd(&state[4], 1u); if (q < LIST_CAP) list[q] = make_uint2(o2, base + 2u); }
    p = o3 >> 8; oo.w = (p > thresh) ? 0.0f : vv.w;
    if (p == thresh) { unsigned q = atomicAdd(&state[4], 1u); if (q < LIST_CAP) list[q] = make_uint2(o3, base + 3u); }
    reinterpret_cast<float4*>(out)[iv] = oo;
  }
  if (blockIdx.x == 0) {
    for (int i = (nvec << 2) + threadIdx.x; i < E; i += 256) {
      float val = v[i];
      unsigned ou = keys ? keys[i] : compute_ou((unsigned)i, val, dp, g);
      unsigned p = ou >> 8;
      float o = (p > thresh) ? 0.0f : val;
      if (p == thresh) { unsigned q = atomicAdd(&state[4], 1u); if (q < LIST_CAP) list[q] = make_uint2(ou, (unsigned)i); }
      out[i] = o;
    }
  }
}

// ============================================================================
// P4: all-pairs rank among ties (key desc, idx asc); zero top r2.
// ============================================================================
__global__ __launch_bounds__(1024) void ties_kernel(
    const uint2* __restrict__ list, const unsigned* __restrict__ state,
    float* __restrict__ out) {
  __shared__ uint2 tile[TIES_TILE];
  unsigned M = min(state[4], LIST_CAP);
  unsigned r = state[3];
  int tid = threadIdx.x;
  for (unsigned e0 = 0; e0 < M; e0 += blockDim.x) {
    unsigned e = e0 + tid;
    bool valid = e < M;
    unsigned my_ou = 0, my_idx = 0;
    if (valid) { uint2 me = list[e]; my_ou = me.x; my_idx = me.y; }
    unsigned rank = 0;
    for (unsigned t0 = 0; t0 < M; t0 += TIES_TILE) {
      unsigned tn = min((unsigned)TIES_TILE, M - t0);
      __syncthreads();
      for (unsigned j = tid; j < tn; j += blockDim.x) tile[j] = list[t0 + j];
      __syncthreads();
      if (valid) {
        for (unsigned j = 0; j < tn; ++j) {
          uint2 o = tile[j];
          rank += (o.x > my_ou || (o.x == my_ou && o.y < my_idx)) ? 1u : 0u;
        }
      }
    }
    if (valid && rank < r) out[my_idx] = 0.0f;
  }
}

// ---------------- launch ----------------------------------------------------
extern "C" void kernel_launch(void* const* d_in, const int* in_sizes, int n_in,
                              void* d_out, int out_size, void* d_ws, size_t ws_size,
                              hipStream_t stream) {
  const float* v  = (const float*)d_in[0];
  const float* dp = (const float*)d_in[1];
  const float* g  = (const float*)d_in[2];
  const int* pct  = (const int*)d_in[3];
  float* out = (float*)d_out;
  int E = in_sizes[0];

  uint8_t* ws = (uint8_t*)d_ws;
  const size_t STATE_OFF = 0;                         // 256 B
  const size_t HIST_OFF  = 1024;                      // 16 KiB
  const size_t LIST_OFF  = 32 * 1024;                 // 2 MiB
  const size_t BH_OFF    = (size_t)4 << 20;           // NB * 16 KiB
  const size_t KEYS_OFF  = (size_t)24 << 20;          // E * 4 B

  int NB = 1024;
  if (ws_size < BH_OFF + (size_t)NB * 16384) {
    size_t avail = ws_size > BH_OFF ? (ws_size - BH_OFF) / 16384 : 0;
    NB = (int)(avail < 1024 ? avail : 1024);
    if (NB < 64) {  // cannot run selection; fail loudly via passthrough
      hipMemcpyAsync(out, v, (size_t)E * 4, hipMemcpyDeviceToDevice, stream);
      return;
    }
  }
  bool use_keys = ws_size >= KEYS_OFF + (size_t)E * 4;

  unsigned* state = (unsigned*)(ws + STATE_OFF);
  unsigned* hist  = (unsigned*)(ws + HIST_OFF);
  uint2*    list  = (uint2*)(ws + LIST_OFF);
  unsigned* bh    = (unsigned*)(ws + BH_OFF);
  unsigned* keys  = use_keys ? (unsigned*)(ws + KEYS_OFF) : nullptr;

  hipMemsetAsync(hist, 0, 4096 * sizeof(unsigned), stream);  // stage-1 hist

  key_hist1_kernel<<<NB, 256, 0, stream>>>(v, dp, g, keys, bh, E);
  reduce_hist_kernel<<<RED_SLICES * 16, 256, 0, stream>>>(bh, hist, NB);
  findbin_kernel<<<1, 1024, 0, stream>>>(hist, state, pct, (long long)E, 0);
  refine_hist_kernel<<<NB, 256, 0, stream>>>(v, dp, g, keys, state, bh, E);
  reduce_hist_kernel<<<RED_SLICES * 16, 256, 0, stream>>>(bh, hist, NB);
  findbin_kernel<<<1, 1024, 0, stream>>>(hist, state, pct, (long long)E, 1);
  output_kernel<<<2048, 256, 0, stream>>>(v, dp, g, keys, out, state, list, E);
  ties_kernel<<<1, 1024, 0, stream>>>(list, state, out);
}